// Round 6
// baseline (438.173 us; speedup 1.0000x reference)
//
#include <hip/hip_runtime.h>

// ---------------- problem constants ----------------
constexpr int N  = 50000;   // nodes
constexpr int E  = 800000;  // edges (without self loops)
constexpr int K  = 256;     // IN_DIM
constexpr int F  = 256;     // HEADS*OUT_DIM
constexpr int H  = 4;       // heads
constexpr float SLOPE = 0.2f;

// Wt rows: 0..255 = W^T (bf16), 256..259 = Wa (att_src fold),
// 260..263 = Wd (att_dst fold), 264..271 = zeros (MFMA padding).
constexpr int WT_ROWS = 272;

// ---------------- workspace layout (bytes, all 16-aligned) ----------------
constexpr size_t OFF_HB   = 0;                                  // N*F bf16
constexpr size_t OFF_WT   = OFF_HB   + (size_t)N * F * 2;       // 272*256 bf16
constexpr size_t OFF_ASRC = OFF_WT   + (size_t)WT_ROWS * K * 2; // N*H f32
constexpr size_t OFF_ADST = OFF_ASRC + (size_t)N * H * 4;       // N*H f32
constexpr size_t OFF_DEG  = OFF_ADST + (size_t)N * H * 4;       // N int
constexpr size_t OFF_OFFS = OFF_DEG  + (size_t)N * 4;           // (N+1) int
constexpr size_t OFF_FLAG = OFF_OFFS + (size_t)(N + 16) * 4;    // 1 int
constexpr size_t OFF_RANK = OFF_FLAG + 64;                      // E uint (packed)
constexpr size_t OFF_CSR  = OFF_RANK + (size_t)E * 4;           // E int

constexpr int HIST_BLOCKS = 256;            // run FIRST for overlap
constexpr int GEMM_BLOCKS = (N + 127) / 128;  // 391

typedef short short8 __attribute__((ext_vector_type(8)));
typedef float floatx4 __attribute__((ext_vector_type(4)));

__device__ __forceinline__ float leaky(float x) {
    return x > 0.f ? x : SLOPE * x;
}
__device__ __forceinline__ float blo(unsigned u) { return __uint_as_float(u << 16); }
__device__ __forceinline__ float bhi(unsigned u) { return __uint_as_float(u & 0xffff0000u); }
__device__ __forceinline__ unsigned short f2b(float f) {
    unsigned u = __float_as_uint(f);
    return (unsigned short)((u + 0x7fffu + ((u >> 16) & 1u)) >> 16);
}
__device__ __forceinline__ unsigned pk2(float a, float b) {
    return (unsigned)f2b(a) | ((unsigned)f2b(b) << 16);
}

__device__ __forceinline__ int edge_at(const void* ei, int is64, size_t i) {
    if (is64) return (int)((const long long*)ei)[i];
    return ((const int*)ei)[i];
}

// ---------------- prep: transpose W, fold att, detect dtype, zero deg ------
// blocks 0..15: transpose tile; 16: fold; 17: detect; 18..66: zero deg
__global__ __launch_bounds__(256)
void prep(const float* __restrict__ Wm, const float* __restrict__ att_src,
          const float* __restrict__ att_dst, const unsigned* __restrict__ ei_words,
          unsigned short* __restrict__ Wt, int* __restrict__ flag,
          int4* __restrict__ zero_region) {
    __shared__ float tile[64][65];
    const int bid = blockIdx.x;
    const int t = threadIdx.x;
    if (bid < 16) {
        const int k0 = (bid & 3) * 64;
        const int n0 = (bid >> 2) * 64;
        const int r = t >> 2;
        const int c4 = (t & 3) * 16;
        #pragma unroll
        for (int i = 0; i < 16; i += 4) {
            float4 v = *reinterpret_cast<const float4*>(
                Wm + (size_t)(k0 + r) * F + n0 + c4 + i);
            tile[r][c4 + i + 0] = v.x;
            tile[r][c4 + i + 1] = v.y;
            tile[r][c4 + i + 2] = v.z;
            tile[r][c4 + i + 3] = v.w;
        }
        __syncthreads();
        unsigned pk[8];
        #pragma unroll
        for (int j = 0; j < 8; ++j)
            pk[j] = pk2(tile[c4 + 2 * j + 0][r], tile[c4 + 2 * j + 1][r]);
        unsigned short* dst = Wt + (size_t)(n0 + r) * K + k0 + c4;
        *reinterpret_cast<uint4*>(dst)     = make_uint4(pk[0], pk[1], pk[2], pk[3]);
        *reinterpret_cast<uint4*>(dst + 8) = make_uint4(pk[4], pk[5], pk[6], pk[7]);
    } else if (bid == 16) {
        const int k = t;  // 0..255
        #pragma unroll
        for (int h = 0; h < H; ++h) {
            const float* wr = Wm + (size_t)k * F + h * 64;
            float s = 0.f, d = 0.f;
            #pragma unroll 8
            for (int c = 0; c < 64; ++c) {
                float w = wr[c];
                s += w * att_src[h * 64 + c];
                d += w * att_dst[h * 64 + c];
            }
            Wt[(size_t)(256 + h) * K + k] = f2b(s);
            Wt[(size_t)(260 + h) * K + k] = f2b(d);
        }
        #pragma unroll
        for (int r = 0; r < 8; ++r) Wt[(size_t)(264 + r) * K + k] = 0;
    } else if (bid == 17) {
        if (t < 64) {
            unsigned v = ei_words[2 * t + 1];
            unsigned long long b = __ballot(v != 0u);
            if (t == 0) *flag = (b == 0ull) ? 1 : 0;
        }
    } else {
        int idx = (bid - 18) * 256 + t;  // 12500 int4 = deg[N]
        if (idx < 12500) zero_region[idx] = make_int4(0, 0, 0, 0);
    }
}

// ---------------- fused: hist+rank (blocks 0..255) + MFMA GEMM (256..646) --
// GEMM: block tile 128 rows x 272 cols, BK=64, A and B staged in LDS.
// Wave w: cols [64w,64w+64) over all 128 rows; fused cols for row chunks
// 2w, 2w+1. Hist blocks first so their atomic latency overlaps the GEMM.
constexpr int LDA = 72;
constexpr int LDW = 72;

__global__ __launch_bounds__(256, 2)
void gemm_hist(const float* __restrict__ X, const unsigned short* __restrict__ Wt,
               unsigned short* __restrict__ Hb, float* __restrict__ asrc,
               float* __restrict__ adst, const void* __restrict__ ei,
               const int* __restrict__ flag, int* __restrict__ deg,
               unsigned* __restrict__ rankpack) {
    __shared__ unsigned short Al[128 * LDA];      // 18432 B
    __shared__ unsigned short Wl[WT_ROWS * LDW];  // 39168 B
    const int tid = threadIdx.x;

    if (blockIdx.x < HIST_BLOCKS) {
        // ---- histogram + rank assignment ----
        const int is64 = *flag;
        for (int i = blockIdx.x * 256 + tid; i < E; i += HIST_BLOCKS * 256) {
            int d = edge_at(ei, is64, (size_t)E + i);
            int r = atomicAdd(&deg[d], 1);
            rankpack[i] = ((unsigned)r << 17) | (unsigned)d;
        }
        return;
    }

    const int wv = tid >> 6, lane = tid & 63;
    const int quad = lane >> 4, l15 = lane & 15;
    const int m0 = (blockIdx.x - HIST_BLOCKS) * 128;

    floatx4 acc[8][4];   // [row chunk i][col chunk j], cols 64*wv + 16j
    #pragma unroll
    for (int i = 0; i < 8; ++i)
        #pragma unroll
        for (int j = 0; j < 4; ++j) acc[i][j] = (floatx4)0.f;
    floatx4 accf[2];     // fused cols 256..271 for row chunks 2wv, 2wv+1
    accf[0] = (floatx4)0.f;
    accf[1] = (floatx4)0.f;

    const int ar = tid >> 1;             // A staging: row 0..127
    const int akc = (tid & 1) * 32;      // k sub-offset 0 / 32
    const bool arow_ok = (m0 + ar) < N;

    for (int k0 = 0; k0 < K; k0 += 64) {
        {   // stage A tile (fp32 -> bf16): 32 floats per thread
            const float4* src = reinterpret_cast<const float4*>(
                X + (size_t)(m0 + ar) * K + k0 + akc);
            unsigned short* dst = &Al[ar * LDA + akc];
            #pragma unroll
            for (int i = 0; i < 4; ++i) {
                float4 va = arow_ok ? src[2 * i]     : make_float4(0.f, 0.f, 0.f, 0.f);
                float4 vb = arow_ok ? src[2 * i + 1] : make_float4(0.f, 0.f, 0.f, 0.f);
                uint4 o = make_uint4(pk2(va.x, va.y), pk2(va.z, va.w),
                                     pk2(vb.x, vb.y), pk2(vb.z, vb.w));
                *reinterpret_cast<uint4*>(dst + i * 8) = o;
            }
        }
        {   // stage W rows 0..255
            const unsigned short* src = Wt + (size_t)tid * K + k0;
            unsigned short* dst = &Wl[tid * LDW];
            #pragma unroll
            for (int i = 0; i < 64; i += 8)
                *reinterpret_cast<int4*>(dst + i) =
                    *reinterpret_cast<const int4*>(src + i);
        }
        if (tid < 16) {  // stage fused rows 256..271
            const unsigned short* src = Wt + (size_t)(256 + tid) * K + k0;
            unsigned short* dst = &Wl[(256 + tid) * LDW];
            #pragma unroll
            for (int i = 0; i < 64; i += 8)
                *reinterpret_cast<int4*>(dst + i) =
                    *reinterpret_cast<const int4*>(src + i);
        }
        __syncthreads();
        #pragma unroll
        for (int kk = 0; kk < 64; kk += 32) {
            short8 a[8];
            #pragma unroll
            for (int i = 0; i < 8; ++i)
                a[i] = *reinterpret_cast<const short8*>(
                    &Al[(i * 16 + l15) * LDA + kk + quad * 8]);
            #pragma unroll
            for (int j = 0; j < 4; ++j) {
                short8 b = *reinterpret_cast<const short8*>(
                    &Wl[(wv * 64 + j * 16 + l15) * LDW + kk + quad * 8]);
                #pragma unroll
                for (int i = 0; i < 8; ++i)
                    acc[i][j] = __builtin_amdgcn_mfma_f32_16x16x32_bf16(
                        a[i], b, acc[i][j], 0, 0, 0);
            }
            {
                short8 bf = *reinterpret_cast<const short8*>(
                    &Wl[(256 + l15) * LDW + kk + quad * 8]);
                accf[0] = __builtin_amdgcn_mfma_f32_16x16x32_bf16(
                    a[2 * wv], bf, accf[0], 0, 0, 0);
                accf[1] = __builtin_amdgcn_mfma_f32_16x16x32_bf16(
                    a[2 * wv + 1], bf, accf[1], 0, 0, 0);
            }
        }
        __syncthreads();
    }
    // epilogue: D layout col=lane&15, row=quad*4+reg
    #pragma unroll
    for (int i = 0; i < 8; ++i) {
        const int rbase = m0 + i * 16 + quad * 4;
        #pragma unroll
        for (int j = 0; j < 4; ++j) {
            const int col = wv * 64 + j * 16 + l15;
            #pragma unroll
            for (int r = 0; r < 4; ++r) {
                int row = rbase + r;
                if (row < N) Hb[(size_t)row * F + col] = f2b(acc[i][j][r]);
            }
        }
    }
    #pragma unroll
    for (int t2 = 0; t2 < 2; ++t2) {
        const int rbase = m0 + (2 * wv + t2) * 16 + quad * 4;
        #pragma unroll
        for (int r = 0; r < 4; ++r) {
            int row = rbase + r;
            if (row < N) {
                if (l15 < 4)      asrc[row * H + l15] = accf[t2][r];
                else if (l15 < 8) adst[row * H + (l15 - 4)] = accf[t2][r];
            }
        }
    }
}

// ---------------- single-block scan of degrees -> CSR offsets --------------
__global__ __launch_bounds__(1024)
void scan_deg(const int* __restrict__ deg, int* __restrict__ offs) {
    __shared__ int sums[1024];
    const int t = threadIdx.x;
    const int lo = t * 52;
    const int hi = min(lo + 52, N);
    int s = 0;
    if (lo < N) {
        const int4* p = reinterpret_cast<const int4*>(deg + lo);
        const int n4 = (hi - lo) >> 2;
        for (int i = 0; i < n4; ++i) {
            int4 v = p[i];
            s += v.x + v.y + v.z + v.w;
        }
    }
    sums[t] = s;
    __syncthreads();
    for (int off = 1; off < 1024; off <<= 1) {
        int v = (t >= off) ? sums[t - off] : 0;
        __syncthreads();
        sums[t] += v;
        __syncthreads();
    }
    int base = sums[t] - s;  // exclusive prefix
    if (lo < N) {
        const int4* p = reinterpret_cast<const int4*>(deg + lo);
        int4* q = reinterpret_cast<int4*>(offs + lo);
        const int n4 = (hi - lo) >> 2;
        for (int i = 0; i < n4; ++i) {
            int4 v = p[i];
            int4 o;
            o.x = base;
            o.y = o.x + v.x;
            o.z = o.y + v.y;
            o.w = o.z + v.z;
            base = o.w + v.w;
            q[i] = o;
        }
    }
    if (t == 0) offs[N] = sums[1023];
}

// ---------------- scatter: atomic-free (rank precomputed) ------------------
__global__ void scatter_edges(const void* __restrict__ ei,
                              const int* __restrict__ flag,
                              const int* __restrict__ offs,
                              const unsigned* __restrict__ rankpack,
                              int* __restrict__ csr) {
    const int is64 = *flag;
    for (int i = blockIdx.x * blockDim.x + threadIdx.x; i < E;
         i += gridDim.x * blockDim.x) {
        unsigned pk = rankpack[i];
        int d = (int)(pk & 0x1ffffu);
        int r = (int)(pk >> 17);
        int s = edge_at(ei, is64, i);
        csr[offs[d] + r] = s;
    }
}

// ---------------- softmax + aggregate (no-max: logits are O(5)) ------------
__global__ __launch_bounds__(256)
void aggregate(const unsigned short* __restrict__ Hb, const float* __restrict__ asrc,
               const float* __restrict__ adst, const int* __restrict__ offs,
               const int* __restrict__ csr, const float* __restrict__ bias,
               float* __restrict__ out) {
    const int wave = threadIdx.x >> 6;
    const int lane = threadIdx.x & 63;
    const int node = blockIdx.x * 4 + wave;
    if (node >= N) return;
    const int hd = lane >> 4;

    const char* hbase = (const char*)Hb;
    const char* abase = (const char*)asrc;
    const unsigned lsh = (unsigned)lane << 3;   // byte offset of lane's 4 ch
    const unsigned hsh = (unsigned)hd << 2;

    const float adsti = adst[node * H + hd];
    const float asrci = *(const float*)(abase + (((unsigned)node << 4) + hsh));
    const float self_logit = leaky(asrci + adsti);
    const int start = offs[node];
    const int end = offs[node + 1];

    float denom = 0.f;
    float ax = 0.f, ay = 0.f, az = 0.f, aw = 0.f;
    int e = start;
    for (; e + 8 <= end; e += 8) {
        unsigned s[8]; float l[8]; uint2 u[8]; float p[8];
        #pragma unroll
        for (int j = 0; j < 8; ++j) s[j] = (unsigned)csr[e + j];
        #pragma unroll
        for (int j = 0; j < 8; ++j)
            l[j] = *(const float*)(abase + ((s[j] << 4) + hsh));
        #pragma unroll
        for (int j = 0; j < 8; ++j)
            u[j] = *(const uint2*)(hbase + ((s[j] << 9) + lsh));
        #pragma unroll
        for (int j = 0; j < 8; ++j) {
            p[j] = __expf(leaky(l[j] + adsti));
            denom += p[j];
            ax += p[j] * blo(u[j].x);
            ay += p[j] * bhi(u[j].x);
            az += p[j] * blo(u[j].y);
            aw += p[j] * bhi(u[j].y);
        }
    }
    for (; e + 2 <= end; e += 2) {
        unsigned s0 = (unsigned)csr[e], s1 = (unsigned)csr[e + 1];
        float l0 = *(const float*)(abase + ((s0 << 4) + hsh));
        float l1 = *(const float*)(abase + ((s1 << 4) + hsh));
        uint2 u0 = *(const uint2*)(hbase + ((s0 << 9) + lsh));
        uint2 u1 = *(const uint2*)(hbase + ((s1 << 9) + lsh));
        float p0 = __expf(leaky(l0 + adsti));
        float p1 = __expf(leaky(l1 + adsti));
        denom += p0 + p1;
        ax += p0 * blo(u0.x) + p1 * blo(u1.x);
        ay += p0 * bhi(u0.x) + p1 * bhi(u1.x);
        az += p0 * blo(u0.y) + p1 * blo(u1.y);
        aw += p0 * bhi(u0.y) + p1 * bhi(u1.y);
    }
    if (e < end) {
        unsigned s0 = (unsigned)csr[e];
        float l0 = *(const float*)(abase + ((s0 << 4) + hsh));
        uint2 u0 = *(const uint2*)(hbase + ((s0 << 9) + lsh));
        float p0 = __expf(leaky(l0 + adsti));
        denom += p0;
        ax += p0 * blo(u0.x);
        ay += p0 * bhi(u0.x);
        az += p0 * blo(u0.y);
        aw += p0 * bhi(u0.y);
    }
    {   // self loop
        float p = __expf(self_logit);
        uint2 u = *(const uint2*)(hbase + (((unsigned)node << 9) + lsh));
        denom += p;
        ax += p * blo(u.x);
        ay += p * bhi(u.x);
        az += p * blo(u.y);
        aw += p * bhi(u.y);
    }
    const float inv = 1.f / (denom + 1e-16f);
    float4 bv = *reinterpret_cast<const float4*>(bias + lane * 4);
    float4 o;
    o.x = fmaxf(ax * inv + bv.x, 0.f);
    o.y = fmaxf(ay * inv + bv.y, 0.f);
    o.z = fmaxf(az * inv + bv.z, 0.f);
    o.w = fmaxf(aw * inv + bv.w, 0.f);
    *reinterpret_cast<float4*>(out + (size_t)node * F + lane * 4) = o;
}

extern "C" void kernel_launch(void* const* d_in, const int* in_sizes, int n_in,
                              void* d_out, int out_size, void* d_ws, size_t ws_size,
                              hipStream_t stream) {
    const float* x       = (const float*)d_in[0];
    const void*  ei      = d_in[1];  // int64 or int32, detected on device
    const float* Wm      = (const float*)d_in[2];
    const float* att_src = (const float*)d_in[3];
    const float* att_dst = (const float*)d_in[4];
    const float* bias    = (const float*)d_in[5];
    float* out = (float*)d_out;

    char* ws = (char*)d_ws;
    unsigned short* hb = (unsigned short*)(ws + OFF_HB);
    unsigned short* wt = (unsigned short*)(ws + OFF_WT);
    float* asrc = (float*)(ws + OFF_ASRC);
    float* adst = (float*)(ws + OFF_ADST);
    int* deg  = (int*)(ws + OFF_DEG);
    int* offs = (int*)(ws + OFF_OFFS);
    int* flag = (int*)(ws + OFF_FLAG);
    unsigned* rankpack = (unsigned*)(ws + OFF_RANK);
    int* csr  = (int*)(ws + OFF_CSR);

    prep<<<67, 256, 0, stream>>>(Wm, att_src, att_dst, (const unsigned*)ei,
                                 wt, flag, (int4*)(ws + OFF_DEG));
    gemm_hist<<<HIST_BLOCKS + GEMM_BLOCKS, 256, 0, stream>>>(
        x, wt, hb, asrc, adst, ei, flag, deg, rankpack);
    scan_deg<<<1, 1024, 0, stream>>>(deg, offs);
    scatter_edges<<<1024, 256, 0, stream>>>(ei, flag, offs, rankpack, csr);
    aggregate<<<(N + 3) / 4, 256, 0, stream>>>(hb, asrc, adst, offs, csr, bias, out);
}

// Round 7
// 269.887 us; speedup vs baseline: 1.6235x; 1.6235x over previous
//
#include <hip/hip_runtime.h>

// ---------------- problem constants ----------------
constexpr int N  = 50000;   // nodes
constexpr int E  = 800000;  // edges (without self loops)
constexpr int K  = 256;     // IN_DIM
constexpr int F  = 256;     // HEADS*OUT_DIM
constexpr int H  = 4;       // heads
constexpr float SLOPE = 0.2f;

// Wt rows: 0..255 = W^T (bf16), 256..259 = Wa (att_src fold),
// 260..263 = Wd (att_dst fold), 264..271 = zeros (MFMA padding).
constexpr int WT_ROWS = 272;

// ---------------- workspace layout (bytes, all 16-aligned) ----------------
constexpr size_t OFF_HB   = 0;                                  // N*F bf16
constexpr size_t OFF_WT   = OFF_HB   + (size_t)N * F * 2;       // 272*256 bf16
constexpr size_t OFF_ASRC = OFF_WT   + (size_t)WT_ROWS * K * 2; // N*H f32
constexpr size_t OFF_ADST = OFF_ASRC + (size_t)N * H * 4;       // N*H f32
constexpr size_t OFF_DEG  = OFF_ADST + (size_t)N * H * 4;       // N int
constexpr size_t OFF_OFFS = OFF_DEG  + (size_t)N * 4;           // (N+1) int
constexpr size_t OFF_FLAG = OFF_OFFS + (size_t)(N + 16) * 4;    // 1 int
constexpr size_t OFF_RANK = OFF_FLAG + 64;                      // E uint (packed)
constexpr size_t OFF_CSR  = OFF_RANK + (size_t)E * 4;           // E int

constexpr int HIST_BLOCKS = 256;             // run FIRST for overlap
constexpr int GEMM_BLOCKS = (N + 63) / 64;   // 782, 64-row tiles (validated R5)

typedef short short8 __attribute__((ext_vector_type(8)));
typedef float floatx4 __attribute__((ext_vector_type(4)));

__device__ __forceinline__ float leaky(float x) {
    return x > 0.f ? x : SLOPE * x;
}
__device__ __forceinline__ float blo(unsigned u) { return __uint_as_float(u << 16); }
__device__ __forceinline__ float bhi(unsigned u) { return __uint_as_float(u & 0xffff0000u); }
__device__ __forceinline__ unsigned short f2b(float f) {
    unsigned u = __float_as_uint(f);
    return (unsigned short)((u + 0x7fffu + ((u >> 16) & 1u)) >> 16);
}
__device__ __forceinline__ unsigned pk2(float a, float b) {
    return (unsigned)f2b(a) | ((unsigned)f2b(b) << 16);
}

__device__ __forceinline__ int edge_at(const void* ei, int is64, size_t i) {
    if (is64) return (int)((const long long*)ei)[i];
    return ((const int*)ei)[i];
}

// ---------------- prep: transpose W, fold att, detect dtype, zero deg ------
// blocks 0..15: transpose tile; 16: fold; 17: detect; 18..66: zero deg
__global__ __launch_bounds__(256)
void prep(const float* __restrict__ Wm, const float* __restrict__ att_src,
          const float* __restrict__ att_dst, const unsigned* __restrict__ ei_words,
          unsigned short* __restrict__ Wt, int* __restrict__ flag,
          int4* __restrict__ zero_region) {
    __shared__ float tile[64][65];
    const int bid = blockIdx.x;
    const int t = threadIdx.x;
    if (bid < 16) {
        const int k0 = (bid & 3) * 64;
        const int n0 = (bid >> 2) * 64;
        const int r = t >> 2;
        const int c4 = (t & 3) * 16;
        #pragma unroll
        for (int i = 0; i < 16; i += 4) {
            float4 v = *reinterpret_cast<const float4*>(
                Wm + (size_t)(k0 + r) * F + n0 + c4 + i);
            tile[r][c4 + i + 0] = v.x;
            tile[r][c4 + i + 1] = v.y;
            tile[r][c4 + i + 2] = v.z;
            tile[r][c4 + i + 3] = v.w;
        }
        __syncthreads();
        unsigned pk[8];
        #pragma unroll
        for (int j = 0; j < 8; ++j)
            pk[j] = pk2(tile[c4 + 2 * j + 0][r], tile[c4 + 2 * j + 1][r]);
        unsigned short* dst = Wt + (size_t)(n0 + r) * K + k0 + c4;
        *reinterpret_cast<uint4*>(dst)     = make_uint4(pk[0], pk[1], pk[2], pk[3]);
        *reinterpret_cast<uint4*>(dst + 8) = make_uint4(pk[4], pk[5], pk[6], pk[7]);
    } else if (bid == 16) {
        const int k = t;  // 0..255
        #pragma unroll
        for (int h = 0; h < H; ++h) {
            const float* wr = Wm + (size_t)k * F + h * 64;
            float s = 0.f, d = 0.f;
            #pragma unroll 8
            for (int c = 0; c < 64; ++c) {
                float w = wr[c];
                s += w * att_src[h * 64 + c];
                d += w * att_dst[h * 64 + c];
            }
            Wt[(size_t)(256 + h) * K + k] = f2b(s);
            Wt[(size_t)(260 + h) * K + k] = f2b(d);
        }
        #pragma unroll
        for (int r = 0; r < 8; ++r) Wt[(size_t)(264 + r) * K + k] = 0;
    } else if (bid == 17) {
        if (t < 64) {
            unsigned v = ei_words[2 * t + 1];
            unsigned long long b = __ballot(v != 0u);
            if (t == 0) *flag = (b == 0ull) ? 1 : 0;
        }
    } else {
        int idx = (bid - 18) * 256 + t;  // 12500 int4 = deg[N]
        if (idx < 12500) zero_region[idx] = make_int4(0, 0, 0, 0);
    }
}

// ---------------- fused: hist+rank (blocks 0..255) + MFMA GEMM (256..1037) --
// GEMM (validated R5 shape): block tile 64 rows x 272 cols, BK=64, A and B
// staged in LDS. Wave w: 64x64 tile (cols 64w..64w+64); wave 3 also fused
// cols 256..271. acc[4][4] -> VGPR=76, no spill (R6's acc[8][4] spilled:
// WRITE_SIZE 54->102 MB). Hist first so atomic latency overlaps GEMM.
constexpr int LDA = 72;
constexpr int LDW = 72;

__global__ __launch_bounds__(256, 3)
void gemm_hist(const float* __restrict__ X, const unsigned short* __restrict__ Wt,
               unsigned short* __restrict__ Hb, float* __restrict__ asrc,
               float* __restrict__ adst, const void* __restrict__ ei,
               const int* __restrict__ flag, int* __restrict__ deg,
               unsigned* __restrict__ rankpack) {
    __shared__ unsigned short Al[64 * LDA];       // 9216 B
    __shared__ unsigned short Wl[WT_ROWS * LDW];  // 39168 B
    const int tid = threadIdx.x;

    if (blockIdx.x < HIST_BLOCKS) {
        // ---- histogram + rank assignment ----
        const int is64 = *flag;
        for (int i = blockIdx.x * 256 + tid; i < E; i += HIST_BLOCKS * 256) {
            int d = edge_at(ei, is64, (size_t)E + i);
            int r = atomicAdd(&deg[d], 1);
            rankpack[i] = ((unsigned)r << 17) | (unsigned)d;
        }
        return;
    }

    const int wv = tid >> 6, lane = tid & 63;
    const int quad = lane >> 4, l15 = lane & 15;
    const int m0 = (blockIdx.x - HIST_BLOCKS) * 64;

    floatx4 acc[4][4];   // [row chunk i][col chunk j], cols 64*wv + 16j
    #pragma unroll
    for (int i = 0; i < 4; ++i)
        #pragma unroll
        for (int j = 0; j < 4; ++j) acc[i][j] = (floatx4)0.f;
    floatx4 accf[4];     // wave 3 only: fused cols 256..271
    #pragma unroll
    for (int i = 0; i < 4; ++i) accf[i] = (floatx4)0.f;

    const int ar = tid >> 2;
    const int akc = (tid & 3) * 16;
    const bool arow_ok = (m0 + ar) < N;

    for (int k0 = 0; k0 < K; k0 += 64) {
        {   // stage A tile (fp32 -> bf16)
            const float* src = X + (size_t)(m0 + ar) * K + k0 + akc;
            unsigned short* dst = &Al[ar * LDA + akc];
            #pragma unroll
            for (int i = 0; i < 16; i += 4) {
                float4 v = arow_ok ? *reinterpret_cast<const float4*>(src + i)
                                   : make_float4(0.f, 0.f, 0.f, 0.f);
                *reinterpret_cast<uint2*>(dst + i) =
                    make_uint2(pk2(v.x, v.y), pk2(v.z, v.w));
            }
        }
        {   // stage W rows 0..255
            const unsigned short* src = Wt + (size_t)tid * K + k0;
            unsigned short* dst = &Wl[tid * LDW];
            #pragma unroll
            for (int i = 0; i < 64; i += 8)
                *reinterpret_cast<int4*>(dst + i) =
                    *reinterpret_cast<const int4*>(src + i);
        }
        if (tid < 16) {  // stage fused rows 256..271
            const unsigned short* src = Wt + (size_t)(256 + tid) * K + k0;
            unsigned short* dst = &Wl[(256 + tid) * LDW];
            #pragma unroll
            for (int i = 0; i < 64; i += 8)
                *reinterpret_cast<int4*>(dst + i) =
                    *reinterpret_cast<const int4*>(src + i);
        }
        __syncthreads();
        #pragma unroll
        for (int kk = 0; kk < 64; kk += 32) {
            short8 a[4];
            #pragma unroll
            for (int i = 0; i < 4; ++i)
                a[i] = *reinterpret_cast<const short8*>(
                    &Al[(i * 16 + l15) * LDA + kk + quad * 8]);
            #pragma unroll
            for (int j = 0; j < 4; ++j) {
                short8 b = *reinterpret_cast<const short8*>(
                    &Wl[(wv * 64 + j * 16 + l15) * LDW + kk + quad * 8]);
                #pragma unroll
                for (int i = 0; i < 4; ++i)
                    acc[i][j] = __builtin_amdgcn_mfma_f32_16x16x32_bf16(
                        a[i], b, acc[i][j], 0, 0, 0);
            }
            if (wv == 3) {
                short8 bf = *reinterpret_cast<const short8*>(
                    &Wl[(256 + l15) * LDW + kk + quad * 8]);
                #pragma unroll
                for (int i = 0; i < 4; ++i)
                    accf[i] = __builtin_amdgcn_mfma_f32_16x16x32_bf16(
                        a[i], bf, accf[i], 0, 0, 0);
            }
        }
        __syncthreads();
    }
    // epilogue: D layout col=lane&15, row=quad*4+reg
    #pragma unroll
    for (int i = 0; i < 4; ++i) {
        const int rbase = m0 + i * 16 + quad * 4;
        #pragma unroll
        for (int j = 0; j < 4; ++j) {
            const int col = wv * 64 + j * 16 + l15;
            #pragma unroll
            for (int r = 0; r < 4; ++r) {
                int row = rbase + r;
                if (row < N) Hb[(size_t)row * F + col] = f2b(acc[i][j][r]);
            }
        }
    }
    if (wv == 3) {
        #pragma unroll
        for (int i = 0; i < 4; ++i) {
            const int rbase = m0 + i * 16 + quad * 4;
            #pragma unroll
            for (int r = 0; r < 4; ++r) {
                int row = rbase + r;
                if (row < N) {
                    if (l15 < 4)      asrc[row * H + l15] = accf[i][r];
                    else if (l15 < 8) adst[row * H + (l15 - 4)] = accf[i][r];
                }
            }
        }
    }
}

// ---------------- single-block scan of degrees -> CSR offsets --------------
__global__ __launch_bounds__(1024)
void scan_deg(const int* __restrict__ deg, int* __restrict__ offs) {
    __shared__ int sums[1024];
    const int t = threadIdx.x;
    const int lo = t * 52;
    const int hi = min(lo + 52, N);
    int s = 0;
    if (lo < N) {
        const int4* p = reinterpret_cast<const int4*>(deg + lo);
        const int n4 = (hi - lo) >> 2;
        for (int i = 0; i < n4; ++i) {
            int4 v = p[i];
            s += v.x + v.y + v.z + v.w;
        }
    }
    sums[t] = s;
    __syncthreads();
    for (int off = 1; off < 1024; off <<= 1) {
        int v = (t >= off) ? sums[t - off] : 0;
        __syncthreads();
        sums[t] += v;
        __syncthreads();
    }
    int base = sums[t] - s;  // exclusive prefix
    if (lo < N) {
        const int4* p = reinterpret_cast<const int4*>(deg + lo);
        int4* q = reinterpret_cast<int4*>(offs + lo);
        const int n4 = (hi - lo) >> 2;
        for (int i = 0; i < n4; ++i) {
            int4 v = p[i];
            int4 o;
            o.x = base;
            o.y = o.x + v.x;
            o.z = o.y + v.y;
            o.w = o.z + v.z;
            base = o.w + v.w;
            q[i] = o;
        }
    }
    if (t == 0) offs[N] = sums[1023];
}

// ---------------- scatter: atomic-free (rank precomputed) ------------------
__global__ void scatter_edges(const void* __restrict__ ei,
                              const int* __restrict__ flag,
                              const int* __restrict__ offs,
                              const unsigned* __restrict__ rankpack,
                              int* __restrict__ csr) {
    const int is64 = *flag;
    for (int i = blockIdx.x * blockDim.x + threadIdx.x; i < E;
         i += gridDim.x * blockDim.x) {
        unsigned pk = rankpack[i];
        int d = (int)(pk & 0x1ffffu);
        int r = (int)(pk >> 17);
        int s = edge_at(ei, is64, i);
        csr[offs[d] + r] = s;
    }
}

// ---------------- softmax + aggregate (no-max: logits are O(5)) ------------
__global__ __launch_bounds__(256)
void aggregate(const unsigned short* __restrict__ Hb, const float* __restrict__ asrc,
               const float* __restrict__ adst, const int* __restrict__ offs,
               const int* __restrict__ csr, const float* __restrict__ bias,
               float* __restrict__ out) {
    const int wave = threadIdx.x >> 6;
    const int lane = threadIdx.x & 63;
    const int node = blockIdx.x * 4 + wave;
    if (node >= N) return;
    const int hd = lane >> 4;

    const char* hbase = (const char*)Hb;
    const char* abase = (const char*)asrc;
    const unsigned lsh = (unsigned)lane << 3;   // byte offset of lane's 4 ch
    const unsigned hsh = (unsigned)hd << 2;

    const float adsti = adst[node * H + hd];
    const float asrci = *(const float*)(abase + (((unsigned)node << 4) + hsh));
    const float self_logit = leaky(asrci + adsti);
    const int start = offs[node];
    const int end = offs[node + 1];

    float denom = 0.f;
    float ax = 0.f, ay = 0.f, az = 0.f, aw = 0.f;
    int e = start;
    for (; e + 8 <= end; e += 8) {
        unsigned s[8]; float l[8]; uint2 u[8]; float p[8];
        #pragma unroll
        for (int j = 0; j < 8; ++j) s[j] = (unsigned)csr[e + j];
        #pragma unroll
        for (int j = 0; j < 8; ++j)
            l[j] = *(const float*)(abase + ((s[j] << 4) + hsh));
        #pragma unroll
        for (int j = 0; j < 8; ++j)
            u[j] = *(const uint2*)(hbase + ((s[j] << 9) + lsh));
        #pragma unroll
        for (int j = 0; j < 8; ++j) {
            p[j] = __expf(leaky(l[j] + adsti));
            denom += p[j];
            ax += p[j] * blo(u[j].x);
            ay += p[j] * bhi(u[j].x);
            az += p[j] * blo(u[j].y);
            aw += p[j] * bhi(u[j].y);
        }
    }
    for (; e + 2 <= end; e += 2) {
        unsigned s0 = (unsigned)csr[e], s1 = (unsigned)csr[e + 1];
        float l0 = *(const float*)(abase + ((s0 << 4) + hsh));
        float l1 = *(const float*)(abase + ((s1 << 4) + hsh));
        uint2 u0 = *(const uint2*)(hbase + ((s0 << 9) + lsh));
        uint2 u1 = *(const uint2*)(hbase + ((s1 << 9) + lsh));
        float p0 = __expf(leaky(l0 + adsti));
        float p1 = __expf(leaky(l1 + adsti));
        denom += p0 + p1;
        ax += p0 * blo(u0.x) + p1 * blo(u1.x);
        ay += p0 * bhi(u0.x) + p1 * bhi(u1.x);
        az += p0 * blo(u0.y) + p1 * blo(u1.y);
        aw += p0 * bhi(u0.y) + p1 * bhi(u1.y);
    }
    if (e < end) {
        unsigned s0 = (unsigned)csr[e];
        float l0 = *(const float*)(abase + ((s0 << 4) + hsh));
        uint2 u0 = *(const uint2*)(hbase + ((s0 << 9) + lsh));
        float p0 = __expf(leaky(l0 + adsti));
        denom += p0;
        ax += p0 * blo(u0.x);
        ay += p0 * bhi(u0.x);
        az += p0 * blo(u0.y);
        aw += p0 * bhi(u0.y);
    }
    {   // self loop
        float p = __expf(self_logit);
        uint2 u = *(const uint2*)(hbase + (((unsigned)node << 9) + lsh));
        denom += p;
        ax += p * blo(u.x);
        ay += p * bhi(u.x);
        az += p * blo(u.y);
        aw += p * bhi(u.y);
    }
    const float inv = 1.f / (denom + 1e-16f);
    float4 bv = *reinterpret_cast<const float4*>(bias + lane * 4);
    float4 o;
    o.x = fmaxf(ax * inv + bv.x, 0.f);
    o.y = fmaxf(ay * inv + bv.y, 0.f);
    o.z = fmaxf(az * inv + bv.z, 0.f);
    o.w = fmaxf(aw * inv + bv.w, 0.f);
    *reinterpret_cast<float4*>(out + (size_t)node * F + lane * 4) = o;
}

extern "C" void kernel_launch(void* const* d_in, const int* in_sizes, int n_in,
                              void* d_out, int out_size, void* d_ws, size_t ws_size,
                              hipStream_t stream) {
    const float* x       = (const float*)d_in[0];
    const void*  ei      = d_in[1];  // int64 or int32, detected on device
    const float* Wm      = (const float*)d_in[2];
    const float* att_src = (const float*)d_in[3];
    const float* att_dst = (const float*)d_in[4];
    const float* bias    = (const float*)d_in[5];
    float* out = (float*)d_out;

    char* ws = (char*)d_ws;
    unsigned short* hb = (unsigned short*)(ws + OFF_HB);
    unsigned short* wt = (unsigned short*)(ws + OFF_WT);
    float* asrc = (float*)(ws + OFF_ASRC);
    float* adst = (float*)(ws + OFF_ADST);
    int* deg  = (int*)(ws + OFF_DEG);
    int* offs = (int*)(ws + OFF_OFFS);
    int* flag = (int*)(ws + OFF_FLAG);
    unsigned* rankpack = (unsigned*)(ws + OFF_RANK);
    int* csr  = (int*)(ws + OFF_CSR);

    prep<<<67, 256, 0, stream>>>(Wm, att_src, att_dst, (const unsigned*)ei,
                                 wt, flag, (int4*)(ws + OFF_DEG));
    gemm_hist<<<HIST_BLOCKS + GEMM_BLOCKS, 256, 0, stream>>>(
        x, wt, hb, asrc, adst, ei, flag, deg, rankpack);
    scan_deg<<<1, 1024, 0, stream>>>(deg, offs);
    scatter_edges<<<1024, 256, 0, stream>>>(ei, flag, offs, rankpack, csr);
    aggregate<<<(N + 3) / 4, 256, 0, stream>>>(hb, asrc, adst, offs, csr, bias, out);
}

// Round 8
// 262.903 us; speedup vs baseline: 1.6667x; 1.0266x over previous
//
#include <hip/hip_runtime.h>

// ---------------- problem constants ----------------
constexpr int N  = 50000;   // nodes
constexpr int E  = 800000;  // edges (without self loops)
constexpr int K  = 256;     // IN_DIM
constexpr int F  = 256;     // HEADS*OUT_DIM
constexpr int H  = 4;       // heads
constexpr float SLOPE = 0.2f;

// Wt rows: 0..255 = W^T (bf16), 256..259 = Wa (att_src fold),
// 260..263 = Wd (att_dst fold), 264..271 = zeros (MFMA padding).
constexpr int WT_ROWS = 272;

// ---------------- workspace layout (bytes, all 16-aligned) ----------------
constexpr size_t OFF_HB   = 0;                                  // N*F bf16
constexpr size_t OFF_WT   = OFF_HB   + (size_t)N * F * 2;       // 272*256 bf16
constexpr size_t OFF_ASRC = OFF_WT   + (size_t)WT_ROWS * K * 2; // N*H f32
constexpr size_t OFF_ADST = OFF_ASRC + (size_t)N * H * 4;       // N*H f32
constexpr size_t OFF_DEG  = OFF_ADST + (size_t)N * H * 4;       // N int
constexpr size_t OFF_OFFS = OFF_DEG  + (size_t)N * 4;           // (N+1) int
constexpr size_t OFF_FLAG = OFF_OFFS + (size_t)(N + 16) * 4;    // 1 int
constexpr size_t OFF_RANK = OFF_FLAG + 64;                      // E uint (packed)
constexpr size_t OFF_CSR  = OFF_RANK + (size_t)E * 4;           // E int

constexpr int HIST_BLOCKS = 128;              // 512-thr blocks, run FIRST
constexpr int GEMM_BLOCKS = (N + 127) / 128;  // 391, 128-row tiles, 8 waves

typedef short short8 __attribute__((ext_vector_type(8)));
typedef float floatx4 __attribute__((ext_vector_type(4)));

__device__ __forceinline__ float leaky(float x) {
    return x > 0.f ? x : SLOPE * x;
}
__device__ __forceinline__ float blo(unsigned u) { return __uint_as_float(u << 16); }
__device__ __forceinline__ float bhi(unsigned u) { return __uint_as_float(u & 0xffff0000u); }
__device__ __forceinline__ unsigned short f2b(float f) {
    unsigned u = __float_as_uint(f);
    return (unsigned short)((u + 0x7fffu + ((u >> 16) & 1u)) >> 16);
}
__device__ __forceinline__ unsigned pk2(float a, float b) {
    return (unsigned)f2b(a) | ((unsigned)f2b(b) << 16);
}

__device__ __forceinline__ int edge_at(const void* ei, int is64, size_t i) {
    if (is64) return (int)((const long long*)ei)[i];
    return ((const int*)ei)[i];
}

// ---------------- prep: transpose W, fold att, detect dtype, zero deg ------
// blocks 0..15: transpose tile; 16: fold; 17: detect; 18..66: zero deg
__global__ __launch_bounds__(256)
void prep(const float* __restrict__ Wm, const float* __restrict__ att_src,
          const float* __restrict__ att_dst, const unsigned* __restrict__ ei_words,
          unsigned short* __restrict__ Wt, int* __restrict__ flag,
          int4* __restrict__ zero_region) {
    __shared__ float tile[64][65];
    const int bid = blockIdx.x;
    const int t = threadIdx.x;
    if (bid < 16) {
        const int k0 = (bid & 3) * 64;
        const int n0 = (bid >> 2) * 64;
        const int r = t >> 2;
        const int c4 = (t & 3) * 16;
        #pragma unroll
        for (int i = 0; i < 16; i += 4) {
            float4 v = *reinterpret_cast<const float4*>(
                Wm + (size_t)(k0 + r) * F + n0 + c4 + i);
            tile[r][c4 + i + 0] = v.x;
            tile[r][c4 + i + 1] = v.y;
            tile[r][c4 + i + 2] = v.z;
            tile[r][c4 + i + 3] = v.w;
        }
        __syncthreads();
        unsigned pk[8];
        #pragma unroll
        for (int j = 0; j < 8; ++j)
            pk[j] = pk2(tile[c4 + 2 * j + 0][r], tile[c4 + 2 * j + 1][r]);
        unsigned short* dst = Wt + (size_t)(n0 + r) * K + k0 + c4;
        *reinterpret_cast<uint4*>(dst)     = make_uint4(pk[0], pk[1], pk[2], pk[3]);
        *reinterpret_cast<uint4*>(dst + 8) = make_uint4(pk[4], pk[5], pk[6], pk[7]);
    } else if (bid == 16) {
        const int k = t;  // 0..255
        #pragma unroll
        for (int h = 0; h < H; ++h) {
            const float* wr = Wm + (size_t)k * F + h * 64;
            float s = 0.f, d = 0.f;
            #pragma unroll 8
            for (int c = 0; c < 64; ++c) {
                float w = wr[c];
                s += w * att_src[h * 64 + c];
                d += w * att_dst[h * 64 + c];
            }
            Wt[(size_t)(256 + h) * K + k] = f2b(s);
            Wt[(size_t)(260 + h) * K + k] = f2b(d);
        }
        #pragma unroll
        for (int r = 0; r < 8; ++r) Wt[(size_t)(264 + r) * K + k] = 0;
    } else if (bid == 17) {
        if (t < 64) {
            unsigned v = ei_words[2 * t + 1];
            unsigned long long b = __ballot(v != 0u);
            if (t == 0) *flag = (b == 0ull) ? 1 : 0;
        }
    } else {
        int idx = (bid - 18) * 256 + t;  // 12500 int4 = deg[N]
        if (idx < 12500) zero_region[idx] = make_int4(0, 0, 0, 0);
    }
}

// ---------------- fused: hist+rank (blocks 0..127) + MFMA GEMM (128..518) --
// GEMM: 512 threads = 8 waves. Block tile 128 rows x 272 cols, BK=64.
// Wave w: rows [(w>>2)*64, +64), cols [(w&3)*64, +64), validated acc[4][4]
// per wave (R6's acc[8][4] spilled). Waves with (w&3)==3 also do fused
// cols 256..271 for their row half. W restaged once per 128 rows (was 64).
constexpr int LDA = 72;
constexpr int LDW = 72;

__global__ __launch_bounds__(512, 4)
void gemm_hist(const float* __restrict__ X, const unsigned short* __restrict__ Wt,
               unsigned short* __restrict__ Hb, float* __restrict__ asrc,
               float* __restrict__ adst, const void* __restrict__ ei,
               const int* __restrict__ flag, int* __restrict__ deg,
               unsigned* __restrict__ rankpack) {
    __shared__ unsigned short Al[128 * LDA];      // 18432 B
    __shared__ unsigned short Wl[WT_ROWS * LDW];  // 39168 B
    const int tid = threadIdx.x;

    if (blockIdx.x < HIST_BLOCKS) {
        // ---- histogram + rank assignment ----
        const int is64 = *flag;
        for (int i = blockIdx.x * 512 + tid; i < E; i += HIST_BLOCKS * 512) {
            int d = edge_at(ei, is64, (size_t)E + i);
            int r = atomicAdd(&deg[d], 1);
            rankpack[i] = ((unsigned)r << 17) | (unsigned)d;
        }
        return;
    }

    const int wv = tid >> 6, lane = tid & 63;
    const int quad = lane >> 4, l15 = lane & 15;
    const int rH = wv >> 2;   // row half 0/1
    const int cQ = wv & 3;    // col quarter
    const int m0 = (blockIdx.x - HIST_BLOCKS) * 128;

    floatx4 acc[4][4];
    #pragma unroll
    for (int i = 0; i < 4; ++i)
        #pragma unroll
        for (int j = 0; j < 4; ++j) acc[i][j] = (floatx4)0.f;
    floatx4 accf[4];     // cQ==3 only: fused cols 256..271
    #pragma unroll
    for (int i = 0; i < 4; ++i) accf[i] = (floatx4)0.f;

    const int ar = tid >> 2;          // A staging: row 0..127
    const int akc = (tid & 3) * 16;
    const bool arow_ok = (m0 + ar) < N;
    const int wr = tid >> 1;          // W staging: row 0..255
    const int wkc = (tid & 1) * 32;

    for (int k0 = 0; k0 < K; k0 += 64) {
        {   // stage A tile (fp32 -> bf16), 16 floats/thread
            const float* src = X + (size_t)(m0 + ar) * K + k0 + akc;
            unsigned short* dst = &Al[ar * LDA + akc];
            #pragma unroll
            for (int i = 0; i < 16; i += 4) {
                float4 v = arow_ok ? *reinterpret_cast<const float4*>(src + i)
                                   : make_float4(0.f, 0.f, 0.f, 0.f);
                *reinterpret_cast<uint2*>(dst + i) =
                    make_uint2(pk2(v.x, v.y), pk2(v.z, v.w));
            }
        }
        {   // stage W rows 0..255, 32 ushort/thread
            const unsigned short* src = Wt + (size_t)wr * K + k0 + wkc;
            unsigned short* dst = &Wl[wr * LDW + wkc];
            #pragma unroll
            for (int i = 0; i < 32; i += 8)
                *reinterpret_cast<int4*>(dst + i) =
                    *reinterpret_cast<const int4*>(src + i);
        }
        if (tid < 32) {  // stage fused rows 256..271
            const int fr = 256 + (tid >> 1);
            const int fk = (tid & 1) * 32;
            const unsigned short* src = Wt + (size_t)fr * K + k0 + fk;
            unsigned short* dst = &Wl[fr * LDW + fk];
            #pragma unroll
            for (int i = 0; i < 32; i += 8)
                *reinterpret_cast<int4*>(dst + i) =
                    *reinterpret_cast<const int4*>(src + i);
        }
        __syncthreads();
        #pragma unroll
        for (int kk = 0; kk < 64; kk += 32) {
            short8 a[4];
            #pragma unroll
            for (int i = 0; i < 4; ++i)
                a[i] = *reinterpret_cast<const short8*>(
                    &Al[(rH * 64 + i * 16 + l15) * LDA + kk + quad * 8]);
            #pragma unroll
            for (int j = 0; j < 4; ++j) {
                short8 b = *reinterpret_cast<const short8*>(
                    &Wl[(cQ * 64 + j * 16 + l15) * LDW + kk + quad * 8]);
                #pragma unroll
                for (int i = 0; i < 4; ++i)
                    acc[i][j] = __builtin_amdgcn_mfma_f32_16x16x32_bf16(
                        a[i], b, acc[i][j], 0, 0, 0);
            }
            if (cQ == 3) {
                short8 bf = *reinterpret_cast<const short8*>(
                    &Wl[(256 + l15) * LDW + kk + quad * 8]);
                #pragma unroll
                for (int i = 0; i < 4; ++i)
                    accf[i] = __builtin_amdgcn_mfma_f32_16x16x32_bf16(
                        a[i], bf, accf[i], 0, 0, 0);
            }
        }
        __syncthreads();
    }
    // epilogue: D layout col=lane&15, row=quad*4+reg
    #pragma unroll
    for (int i = 0; i < 4; ++i) {
        const int rbase = m0 + rH * 64 + i * 16 + quad * 4;
        #pragma unroll
        for (int j = 0; j < 4; ++j) {
            const int col = cQ * 64 + j * 16 + l15;
            #pragma unroll
            for (int r = 0; r < 4; ++r) {
                int row = rbase + r;
                if (row < N) Hb[(size_t)row * F + col] = f2b(acc[i][j][r]);
            }
        }
    }
    if (cQ == 3) {
        #pragma unroll
        for (int i = 0; i < 4; ++i) {
            const int rbase = m0 + rH * 64 + i * 16 + quad * 4;
            #pragma unroll
            for (int r = 0; r < 4; ++r) {
                int row = rbase + r;
                if (row < N) {
                    if (l15 < 4)      asrc[row * H + l15] = accf[i][r];
                    else if (l15 < 8) adst[row * H + (l15 - 4)] = accf[i][r];
                }
            }
        }
    }
}

// ---------------- single-block scan of degrees -> CSR offsets --------------
__global__ __launch_bounds__(1024)
void scan_deg(const int* __restrict__ deg, int* __restrict__ offs) {
    __shared__ int sums[1024];
    const int t = threadIdx.x;
    const int lo = t * 52;
    const int hi = min(lo + 52, N);
    int s = 0;
    if (lo < N) {
        const int4* p = reinterpret_cast<const int4*>(deg + lo);
        const int n4 = (hi - lo) >> 2;
        for (int i = 0; i < n4; ++i) {
            int4 v = p[i];
            s += v.x + v.y + v.z + v.w;
        }
    }
    sums[t] = s;
    __syncthreads();
    for (int off = 1; off < 1024; off <<= 1) {
        int v = (t >= off) ? sums[t - off] : 0;
        __syncthreads();
        sums[t] += v;
        __syncthreads();
    }
    int base = sums[t] - s;  // exclusive prefix
    if (lo < N) {
        const int4* p = reinterpret_cast<const int4*>(deg + lo);
        int4* q = reinterpret_cast<int4*>(offs + lo);
        const int n4 = (hi - lo) >> 2;
        for (int i = 0; i < n4; ++i) {
            int4 v = p[i];
            int4 o;
            o.x = base;
            o.y = o.x + v.x;
            o.z = o.y + v.y;
            o.w = o.z + v.z;
            base = o.w + v.w;
            q[i] = o;
        }
    }
    if (t == 0) offs[N] = sums[1023];
}

// ---------------- scatter: atomic-free (rank precomputed) ------------------
__global__ void scatter_edges(const void* __restrict__ ei,
                              const int* __restrict__ flag,
                              const int* __restrict__ offs,
                              const unsigned* __restrict__ rankpack,
                              int* __restrict__ csr) {
    const int is64 = *flag;
    for (int i = blockIdx.x * blockDim.x + threadIdx.x; i < E;
         i += gridDim.x * blockDim.x) {
        unsigned pk = rankpack[i];
        int d = (int)(pk & 0x1ffffu);
        int r = (int)(pk >> 17);
        int s = edge_at(ei, is64, i);
        csr[offs[d] + r] = s;
    }
}

// ---------------- softmax + aggregate: TWO waves per node ------------------
// Latency-bound gather (R7: 3.95 TB/s vs ~6 ceiling): split each node's edge
// list across 2 waves (contiguous halves), combine partials through LDS.
__global__ __launch_bounds__(256)
void aggregate(const unsigned short* __restrict__ Hb, const float* __restrict__ asrc,
               const float* __restrict__ adst, const int* __restrict__ offs,
               const int* __restrict__ csr, const float* __restrict__ bias,
               float* __restrict__ out) {
    __shared__ float part[2][64][5];
    const int wave = threadIdx.x >> 6;
    const int lane = threadIdx.x & 63;
    const int slot = wave >> 1;     // node slot within block
    const int role = wave & 1;      // 0 = first half + self + epilogue
    const int node = blockIdx.x * 2 + slot;   // 25000 blocks * 2 = N exactly
    const int hd = lane >> 4;

    const char* hbase = (const char*)Hb;
    const char* abase = (const char*)asrc;
    const unsigned lsh = (unsigned)lane << 3;   // byte offset of lane's 4 ch
    const unsigned hsh = (unsigned)hd << 2;

    const float adsti = adst[node * H + hd];
    const int start = offs[node];
    const int end = offs[node + 1];
    const int half = (end - start) >> 1;
    const int eb = role == 0 ? start : start + half;
    const int ee = role == 0 ? start + half : end;

    float denom = 0.f;
    float ax = 0.f, ay = 0.f, az = 0.f, aw = 0.f;
    int e = eb;
    for (; e + 8 <= ee; e += 8) {
        unsigned s[8]; float l[8]; uint2 u[8]; float p[8];
        #pragma unroll
        for (int j = 0; j < 8; ++j) s[j] = (unsigned)csr[e + j];
        #pragma unroll
        for (int j = 0; j < 8; ++j)
            l[j] = *(const float*)(abase + ((s[j] << 4) + hsh));
        #pragma unroll
        for (int j = 0; j < 8; ++j)
            u[j] = *(const uint2*)(hbase + ((s[j] << 9) + lsh));
        #pragma unroll
        for (int j = 0; j < 8; ++j) {
            p[j] = __expf(leaky(l[j] + adsti));
            denom += p[j];
            ax += p[j] * blo(u[j].x);
            ay += p[j] * bhi(u[j].x);
            az += p[j] * blo(u[j].y);
            aw += p[j] * bhi(u[j].y);
        }
    }
    for (; e + 2 <= ee; e += 2) {
        unsigned s0 = (unsigned)csr[e], s1 = (unsigned)csr[e + 1];
        float l0 = *(const float*)(abase + ((s0 << 4) + hsh));
        float l1 = *(const float*)(abase + ((s1 << 4) + hsh));
        uint2 u0 = *(const uint2*)(hbase + ((s0 << 9) + lsh));
        uint2 u1 = *(const uint2*)(hbase + ((s1 << 9) + lsh));
        float p0 = __expf(leaky(l0 + adsti));
        float p1 = __expf(leaky(l1 + adsti));
        denom += p0 + p1;
        ax += p0 * blo(u0.x) + p1 * blo(u1.x);
        ay += p0 * bhi(u0.x) + p1 * bhi(u1.x);
        az += p0 * blo(u0.y) + p1 * blo(u1.y);
        aw += p0 * bhi(u0.y) + p1 * bhi(u1.y);
    }
    if (e < ee) {
        unsigned s0 = (unsigned)csr[e];
        float l0 = *(const float*)(abase + ((s0 << 4) + hsh));
        uint2 u0 = *(const uint2*)(hbase + ((s0 << 9) + lsh));
        float p0 = __expf(leaky(l0 + adsti));
        denom += p0;
        ax += p0 * blo(u0.x);
        ay += p0 * bhi(u0.x);
        az += p0 * blo(u0.y);
        aw += p0 * bhi(u0.y);
    }
    if (role == 0) {   // self loop
        float asrci = *(const float*)(abase + (((unsigned)node << 4) + hsh));
        float p = __expf(leaky(asrci + adsti));
        uint2 u = *(const uint2*)(hbase + (((unsigned)node << 9) + lsh));
        denom += p;
        ax += p * blo(u.x);
        ay += p * bhi(u.x);
        az += p * blo(u.y);
        aw += p * bhi(u.y);
    } else {
        part[slot][lane][0] = ax;
        part[slot][lane][1] = ay;
        part[slot][lane][2] = az;
        part[slot][lane][3] = aw;
        part[slot][lane][4] = denom;
    }
    __syncthreads();
    if (role == 0) {
        ax += part[slot][lane][0];
        ay += part[slot][lane][1];
        az += part[slot][lane][2];
        aw += part[slot][lane][3];
        denom += part[slot][lane][4];
        const float inv = 1.f / (denom + 1e-16f);
        float4 bv = *reinterpret_cast<const float4*>(bias + lane * 4);
        float4 o;
        o.x = fmaxf(ax * inv + bv.x, 0.f);
        o.y = fmaxf(ay * inv + bv.y, 0.f);
        o.z = fmaxf(az * inv + bv.z, 0.f);
        o.w = fmaxf(aw * inv + bv.w, 0.f);
        *reinterpret_cast<float4*>(out + (size_t)node * F + lane * 4) = o;
    }
}

extern "C" void kernel_launch(void* const* d_in, const int* in_sizes, int n_in,
                              void* d_out, int out_size, void* d_ws, size_t ws_size,
                              hipStream_t stream) {
    const float* x       = (const float*)d_in[0];
    const void*  ei      = d_in[1];  // int64 or int32, detected on device
    const float* Wm      = (const float*)d_in[2];
    const float* att_src = (const float*)d_in[3];
    const float* att_dst = (const float*)d_in[4];
    const float* bias    = (const float*)d_in[5];
    float* out = (float*)d_out;

    char* ws = (char*)d_ws;
    unsigned short* hb = (unsigned short*)(ws + OFF_HB);
    unsigned short* wt = (unsigned short*)(ws + OFF_WT);
    float* asrc = (float*)(ws + OFF_ASRC);
    float* adst = (float*)(ws + OFF_ADST);
    int* deg  = (int*)(ws + OFF_DEG);
    int* offs = (int*)(ws + OFF_OFFS);
    int* flag = (int*)(ws + OFF_FLAG);
    unsigned* rankpack = (unsigned*)(ws + OFF_RANK);
    int* csr  = (int*)(ws + OFF_CSR);

    prep<<<67, 256, 0, stream>>>(Wm, att_src, att_dst, (const unsigned*)ei,
                                 wt, flag, (int4*)(ws + OFF_DEG));
    gemm_hist<<<HIST_BLOCKS + GEMM_BLOCKS, 512, 0, stream>>>(
        x, wt, hb, asrc, adst, ei, flag, deg, rankpack);
    scan_deg<<<1, 1024, 0, stream>>>(deg, offs);
    scatter_edges<<<1024, 256, 0, stream>>>(ei, flag, offs, rankpack, csr);
    aggregate<<<N / 2, 256, 0, stream>>>(hb, asrc, adst, offs, csr, bias, out);
}